// Round 12
// baseline (1537.392 us; speedup 1.0000x reference)
//
#include <hip/hip_runtime.h>
#include <cstdint>

#define SLEN 1024
#define BATCH 64
#define EDIM 256
#define HDIM 128   // hidden per direction
#define GDIM 512   // 4*HDIM
#define NTAG 4

typedef float f2 __attribute__((ext_vector_type(2)));

// ---------------------------------------------------------------------------
// ws layout (floats), double-buffered Z chunks:
//   Z0 : [L][B][1024]   Z1 : [L][B][1024]
//   H  : [S][B][256]    16777216
//   F  : [S][B][4]        262144
//   ST : [2][B][256]       32768
// ---------------------------------------------------------------------------

__device__ __forceinline__ float sigm_f(float x) {
    return 1.0f / (1.0f + __expf(-x));
}
__device__ __forceinline__ float tanh_f(float x) {
    return 1.0f - 2.0f / (1.0f + __expf(2.0f * x));
}

template <int CTRL>
__device__ __forceinline__ float quad_perm(float x) {
    return __int_as_float(
        __builtin_amdgcn_mov_dpp(__float_as_int(x), CTRL, 0xF, 0xF, true));
}
#define QP_XOR1 0xB1   // quad_perm [1,0,3,2]
#define QP_XOR2 0x4E   // quad_perm [2,3,0,1]

// ---------------------------------------------------------------------------
// gemm body for one S-chunk tile. smem = 64KB scratch (As | Bs).
// Micro-tile reads use the 4+4 split (t*4 and 64+t*4) so Bs reads are 2-way
// max bank aliasing (free) instead of 4-way at t*8 (r11: 1.05e7 conflicts).
// ---------------------------------------------------------------------------
__device__ __forceinline__ void gemm_body(
    float* smem, int mt, int nt,
    const int* __restrict__ sent, const float* __restrict__ embed,
    const float* __restrict__ w_ih_f, const float* __restrict__ w_ih_r,
    const float* __restrict__ b_ih_f, const float* __restrict__ b_hh_f,
    const float* __restrict__ b_ih_r, const float* __restrict__ b_hh_r,
    float* __restrict__ Z, int base_f, int base_r)
{
    float* As = smem;
    float* Bs = smem + 64 * 128;

    const int t   = threadIdx.x;
    const int dir = nt >> 2;
    const float* W  = dir ? w_ih_r : w_ih_f;
    const float* bi = dir ? b_ih_r : b_ih_f;
    const float* bh = dir ? b_hh_r : b_hh_f;
    const int ncol = (nt & 3) * 128;
    const int r0   = mt * 128;

    const int srow = t >> 1;
    const int half = t & 1;
    const int r_loc = r0 + srow;
    const int s_loc = r_loc >> 6;
    const int b_    = r_loc & 63;
    const int s_glob = (dir ? base_r : base_f) + s_loc;
    const int tok = sent[b_ * SLEN + s_glob];
    const float* arow = embed + (size_t)tok * EDIM + half * 32;
    const float* brow = W + (size_t)(ncol + srow) * EDIM + half * 32;

    const int tx = t & 15, ty = t >> 4;

    f2 acc[8][4];
    #pragma unroll
    for (int i = 0; i < 8; ++i)
        #pragma unroll
        for (int jj = 0; jj < 4; ++jj) { acc[i][jj] = (f2)(0.0f); }

    for (int kt = 0; kt < 4; ++kt) {
        const int k0 = kt * 64;
        __syncthreads();
        #pragma unroll
        for (int i = 0; i < 8; ++i) {
            float4 v = *(const float4*)(arow + k0 + i * 4);
            int kk = half * 32 + i * 4;
            As[(kk + 0) * 128 + srow] = v.x;
            As[(kk + 1) * 128 + srow] = v.y;
            As[(kk + 2) * 128 + srow] = v.z;
            As[(kk + 3) * 128 + srow] = v.w;
        }
        #pragma unroll
        for (int i = 0; i < 8; ++i) {
            float4 v = *(const float4*)(brow + k0 + i * 4);
            int kk = half * 32 + i * 4;
            Bs[(kk + 0) * 128 + srow] = v.x;
            Bs[(kk + 1) * 128 + srow] = v.y;
            Bs[(kk + 2) * 128 + srow] = v.z;
            Bs[(kk + 3) * 128 + srow] = v.w;
        }
        __syncthreads();

        #pragma unroll 8
        for (int k = 0; k < 64; ++k) {
            const float4 a0 = *(const float4*)&As[k * 128 + ty * 4];
            const float4 a1 = *(const float4*)&As[k * 128 + 64 + ty * 4];
            const float4 bq0 = *(const float4*)&Bs[k * 128 + tx * 4];
            const float4 bq1 = *(const float4*)&Bs[k * 128 + 64 + tx * 4];
            float av[8] = {a0.x, a0.y, a0.z, a0.w, a1.x, a1.y, a1.z, a1.w};
            f2 bv[4];
            bv[0].x = bq0.x; bv[0].y = bq0.y;
            bv[1].x = bq0.z; bv[1].y = bq0.w;
            bv[2].x = bq1.x; bv[2].y = bq1.y;
            bv[3].x = bq1.z; bv[3].y = bq1.w;
            #pragma unroll
            for (int i = 0; i < 8; ++i) {
                f2 as; as.x = av[i]; as.y = av[i];
                #pragma unroll
                for (int jj = 0; jj < 4; ++jj)
                    acc[i][jj] += as * bv[jj];   // v_pk_fma_f32
            }
        }
    }

    float bias0[4], bias1[4];
    #pragma unroll
    for (int j = 0; j < 4; ++j) {
        bias0[j] = bi[ncol + tx * 4 + j] + bh[ncol + tx * 4 + j];
        bias1[j] = bi[ncol + 64 + tx * 4 + j] + bh[ncol + 64 + tx * 4 + j];
    }

    #pragma unroll
    for (int i = 0; i < 8; ++i) {
        const int row = r0 + ((i < 4) ? (ty * 4 + i) : (64 + ty * 4 + i - 4));
        float* zp = Z + (size_t)row * 1024 + dir * 512 + ncol;
        float4 o0, o1;
        o0.x = acc[i][0].x + bias0[0]; o0.y = acc[i][0].y + bias0[1];
        o0.z = acc[i][1].x + bias0[2]; o0.w = acc[i][1].y + bias0[3];
        o1.x = acc[i][2].x + bias1[0]; o1.y = acc[i][2].y + bias1[1];
        o1.z = acc[i][3].x + bias1[2]; o1.w = acc[i][3].y + bias1[3];
        *(float4*)(zp + tx * 4)      = o0;
        *(float4*)(zp + 64 + tx * 4) = o1;
    }
}

// ---------------------------------------------------------------------------
// LSTM body (v8): r6-v3 structure + Z staged through LDS.
// The 64 persistent zcur/znxt VGPRs are gone: per 4-step group, wave w stages
// step (t0+4+w)'s 512 z-floats global->LDS (transient regs), consumed as
// broadcast-pattern ds_read_b32. Register demand ~250 -> ~190, so w2 (128
// floats) stays (mostly) arch-VGPR-resident instead of AGPR-split.
// smem carve: sh_h = smem[0..320), sh_z = smem[320..4416).
// ---------------------------------------------------------------------------
__device__ __forceinline__ void lstm_body(
    float* smem,
    const float* __restrict__ Z, const float* __restrict__ w_hh_f,
    const float* __restrict__ w_hh_r, float* __restrict__ H,
    float* __restrict__ ST, int base_f, int base_r, int L, int first)
{
    float* sh_h = smem;          // [2][160]
    float* sh_z = smem + 320;    // [2][4][512]

    const int bid = blockIdx.x;
    const int b   = bid & 63;
    const int dir = bid >> 6;
    const int q   = threadIdx.x;
    const int p   = q & 3;
    const int Q   = q >> 2;
    const int uA  = Q;
    const int uB  = Q + 64;
    const int wv  = q >> 6;      // wave id 0..3
    const int ln  = q & 63;      // lane id

    const float* Whh = dir ? w_hh_r : w_hh_f;

    f2 w2[2][4][16];
    #pragma unroll
    for (int u2 = 0; u2 < 2; ++u2) {
        const int u = u2 ? uB : uA;
        #pragma unroll
        for (int g = 0; g < 4; ++g) {
            const float4* src =
                (const float4*)(Whh + ((size_t)(g * 128 + u) * 128 + p * 32));
            #pragma unroll
            for (int i = 0; i < 8; ++i) {
                float4 v = src[i];
                w2[u2][g][2 * i].x     = v.x; w2[u2][g][2 * i].y     = v.y;
                w2[u2][g][2 * i + 1].x = v.z; w2[u2][g][2 * i + 1].y = v.w;
            }
        }
    }

    float* stp = ST + (size_t)(dir * 64 + b) * 256;
    if (q < 128)
        sh_h[(q >> 5) * 36 + (q & 31)] = first ? 0.0f : stp[q];
    float cA = first ? 0.0f : stp[128 + uA];
    float cB = first ? 0.0f : stp[128 + uB];

    const float* Zbase = Z + (size_t)b * 1024 + dir * 512;

    // stage group 0 (steps 0..3): wave wv stages step wv (512 floats)
    {
        const int s_loc = dir ? (L - 1 - wv) : wv;
        const float4* zp = (const float4*)(Zbase + (size_t)s_loc * 65536);
        float4 v0 = zp[ln];
        float4 v1 = zp[64 + ln];
        float* dst = sh_z + wv * 512;
        *(float4*)(dst + 4 * ln)       = v0;
        *(float4*)(dst + 256 + 4 * ln) = v1;
    }
    __syncthreads();

    float hAo[4], hBo[4];

    for (int t0 = 0; t0 < L; t0 += 4) {
        const int cb = (t0 >> 2) & 1;
        const bool more = (t0 + 4 < L);
        if (more) {
            const int tt = t0 + 4 + wv;
            const int s_loc = dir ? (L - 1 - tt) : tt;
            const float4* zp = (const float4*)(Zbase + (size_t)s_loc * 65536);
            float4 v0 = zp[ln];
            float4 v1 = zp[64 + ln];
            float* dst = sh_z + (cb ^ 1) * 2048 + wv * 512;
            *(float4*)(dst + 4 * ln)       = v0;
            *(float4*)(dst + 256 + 4 * ln) = v1;
        }

        #pragma unroll
        for (int dt = 0; dt < 4; ++dt) {
            const int t = t0 + dt;
            const float4* hp = (const float4*)(sh_h + (t & 1) * 160 + p * 36);
            const float* zs = sh_z + cb * 2048 + dt * 512;
            f2 hv[16];
            #pragma unroll
            for (int i = 0; i < 8; ++i) {
                float4 v = hp[i];
                hv[2 * i].x     = v.x; hv[2 * i].y     = v.y;
                hv[2 * i + 1].x = v.z; hv[2 * i + 1].y = v.w;
            }
            float z8[2][4];
            #pragma unroll
            for (int u2 = 0; u2 < 2; ++u2) {
                #pragma unroll
                for (int g = 0; g < 4; ++g) {
                    f2 a = (f2)(0.0f);
                    #pragma unroll
                    for (int i = 0; i < 16; ++i)
                        a += w2[u2][g][i] * hv[i];   // v_pk_fma_f32
                    float v = a.x + a.y;
                    v += quad_perm<QP_XOR1>(v);
                    v += quad_perm<QP_XOR2>(v);
                    z8[u2][g] = v + zs[g * 128 + u2 * 64 + Q];
                }
            }
            float iA = sigm_f(z8[0][0]), fA = sigm_f(z8[0][1]);
            float gA = tanh_f(z8[0][2]), oA = sigm_f(z8[0][3]);
            cA = fA * cA + iA * gA;
            float hA = oA * tanh_f(cA);
            float iB = sigm_f(z8[1][0]), fB = sigm_f(z8[1][1]);
            float gB = tanh_f(z8[1][2]), oB = sigm_f(z8[1][3]);
            cB = fB * cB + iB * gB;
            float hB = oB * tanh_f(cB);
            hAo[dt] = hA; hBo[dt] = hB;

            if (p == 0) {
                float* hn = sh_h + ((t + 1) & 1) * 160;
                hn[(uA >> 5) * 36 + (uA & 31)] = hA;
                hn[(uB >> 5) * 36 + (uB & 31)] = hB;
            }
            __syncthreads();
        }

        if (p == 0) {
            #pragma unroll
            for (int dt = 0; dt < 4; ++dt) {
                const int t = t0 + dt;
                const int s_glob = dir ? (base_r + (L - 1 - t)) : (base_f + t);
                float* hg = H + ((size_t)s_glob * 64 + b) * 256 + dir * 128;
                hg[uA] = hAo[dt];
                hg[uB] = hBo[dt];
            }
        }
    }

    if (p == 0) {
        stp[uA] = hAo[3];  stp[uB] = hBo[3];
        stp[128 + uA] = cA; stp[128 + uB] = cB;
    }
}

// ---------------------------------------------------------------------------
// Fused kernel: blocks 0..127 = lstm chunk c (Zr); blocks 128.. = gemm
// chunk c+1 (Zw). Shared 64KB smem union keeps 2 blocks/CU co-resident.
// ---------------------------------------------------------------------------
__global__ __launch_bounds__(256) void fused_lstm_gemm(
    const int* __restrict__ sent, const float* __restrict__ embed,
    const float* __restrict__ w_ih_f, const float* __restrict__ w_ih_r,
    const float* __restrict__ b_ih_f, const float* __restrict__ b_hh_f,
    const float* __restrict__ b_ih_r, const float* __restrict__ b_hh_r,
    float* __restrict__ Zw, int gbase_f, int gbase_r, int mtiles,
    const float* __restrict__ Zr, const float* __restrict__ w_hh_f,
    const float* __restrict__ w_hh_r, float* __restrict__ H,
    float* __restrict__ ST, int lbase_f, int lbase_r, int L, int first)
{
    __shared__ __align__(16) float smem[64 * 128 * 2];   // 64 KB

    if (blockIdx.x < 128) {
        lstm_body(smem, Zr, w_hh_f, w_hh_r, H, ST, lbase_f, lbase_r, L, first);
    } else {
        const int g  = blockIdx.x - 128;
        const int mt = g % mtiles;
        const int nt = g / mtiles;
        gemm_body(smem, mt, nt, sent, embed, w_ih_f, w_ih_r,
                  b_ih_f, b_hh_f, b_ih_r, b_hh_r, Zw, gbase_f, gbase_r);
    }
}

// standalone gemm (pipeline prologue)
__global__ __launch_bounds__(256) void gemm_zin(
    const int* __restrict__ sent, const float* __restrict__ embed,
    const float* __restrict__ w_ih_f, const float* __restrict__ w_ih_r,
    const float* __restrict__ b_ih_f, const float* __restrict__ b_hh_f,
    const float* __restrict__ b_ih_r, const float* __restrict__ b_hh_r,
    float* __restrict__ Z, int base_f, int base_r)
{
    __shared__ __align__(16) float smem[64 * 128 * 2];
    gemm_body(smem, blockIdx.x, blockIdx.y, sent, embed, w_ih_f, w_ih_r,
              b_ih_f, b_hh_f, b_ih_r, b_hh_r, Z, base_f, base_r);
}

// ---------------------------------------------------------------------------
// Kernel 3: emissions  F[r][t] = H[r] . w_out[t] + b_out[t]
// ---------------------------------------------------------------------------
__global__ __launch_bounds__(256) void emissions_k(
    const float* __restrict__ H, const float* __restrict__ w_out,
    const float* __restrict__ b_out, float* __restrict__ F)
{
    const int gid = blockIdx.x * 256 + threadIdx.x;
    const int r   = gid >> 2;
    const int tg  = gid & 3;
    const float4* h4 = (const float4*)(H + (size_t)r * 256);
    const float4* w4 = (const float4*)(w_out + (size_t)tg * 256);
    float a0 = 0.f, a1 = 0.f, a2 = 0.f, a3 = 0.f;
    #pragma unroll 8
    for (int k = 0; k < 64; ++k) {
        float4 h = h4[k], w = w4[k];
        a0 = fmaf(h.x, w.x, a0); a1 = fmaf(h.y, w.y, a1);
        a2 = fmaf(h.z, w.z, a2); a3 = fmaf(h.w, w.w, a3);
    }
    F[gid] = ((a0 + a1) + (a2 + a3)) + b_out[tg];
}

// ---------------------------------------------------------------------------
// Kernel 4: Viterbi. One block (1 wave) per batch.
// ---------------------------------------------------------------------------
__device__ __forceinline__ unsigned compose_map(unsigned a, unsigned b) {
    unsigned r = 0;
    #pragma unroll
    for (int jj = 0; jj < 4; ++jj) {
        unsigned bj = (b >> (jj * 8)) & 3u;
        unsigned aj = (a >> (bj * 8)) & 3u;
        r |= aj << (jj * 8);
    }
    return r;
}

__global__ __launch_bounds__(64) void viterbi_k(
    const float* __restrict__ F, const float* __restrict__ start_t,
    const float* __restrict__ end_t, const float* __restrict__ trans,
    int* __restrict__ out)
{
    const int b    = blockIdx.x;
    const int lane = threadIdx.x;
    __shared__ __align__(16) float sfeat[SLEN][NTAG];
    __shared__ unsigned sbp[SLEN];

    #pragma unroll
    for (int i = 0; i < 16; ++i) {
        int s = i * 64 + lane;
        ((float4*)sfeat)[s] = *(const float4*)(F + ((size_t)s * BATCH + b) * NTAG);
    }
    __syncthreads();

    const int cur = lane & 3;
    float tr0 = trans[0 * 4 + cur], tr1 = trans[1 * 4 + cur];
    float tr2 = trans[2 * 4 + cur], tr3 = trans[3 * 4 + cur];
    float sc = start_t[cur] + sfeat[0][cur];

    for (int s = 1; s < SLEN; ++s) {
        float ft = sfeat[s][cur];
        float s0 = __shfl(sc, 0), s1 = __shfl(sc, 1);
        float s2 = __shfl(sc, 2), s3 = __shfl(sc, 3);
        float c0 = s0 + tr0, c1 = s1 + tr1, c2 = s2 + tr2, c3 = s3 + tr3;
        float best = c0; int arg = 0;
        if (c1 > best) { best = c1; arg = 1; }
        if (c2 > best) { best = c2; arg = 2; }
        if (c3 > best) { best = c3; arg = 3; }
        sc = best + ft;
        unsigned bp = (unsigned)arg;
        unsigned b0 = __shfl(bp, 0), b1 = __shfl(bp, 1);
        unsigned b2 = __shfl(bp, 2), b3 = __shfl(bp, 3);
        if (lane == 0) sbp[s] = b0 | (b1 << 8) | (b2 << 16) | (b3 << 24);
    }
    sc += end_t[cur];
    float f0 = __shfl(sc, 0), f1 = __shfl(sc, 1);
    float f2v = __shfl(sc, 2), f3 = __shfl(sc, 3);
    int last = 0; float bb = f0;
    if (f1 > bb)  { bb = f1;  last = 1; }
    if (f2v > bb) { bb = f2v; last = 2; }
    if (f3 > bb)  { bb = f3;  last = 3; }
    __syncthreads();

    unsigned m[16];
    #pragma unroll
    for (int k = 0; k < 16; ++k) {
        int s = lane * 16 + k;
        m[k] = (s >= 1) ? sbp[s] : 0x03020100u;
    }
    unsigned G = m[15];
    #pragma unroll
    for (int k = 14; k >= 0; --k) G = compose_map(m[k], G);
    unsigned R = G;
    #pragma unroll
    for (int d = 1; d < 64; d <<= 1) {
        unsigned oo = __shfl_down(R, d);
        if (lane + d < 64) R = compose_map(R, oo);
    }
    unsigned P = __shfl_down(R, 1);
    if (lane == 63) P = 0x03020100u;

    int tcur = (int)((P >> (last * 8)) & 3u);
    int* ob = out + b * SLEN + lane * 16;
    ob[15] = tcur;
    #pragma unroll
    for (int k = 15; k >= 1; --k) {
        tcur = (int)((m[k] >> (tcur * 8)) & 3u);
        ob[k - 1] = tcur;
    }
}

// ---------------------------------------------------------------------------
extern "C" void kernel_launch(void* const* d_in, const int* in_sizes, int n_in,
                              void* d_out, int out_size, void* d_ws, size_t ws_size,
                              hipStream_t stream)
{
    const int*   sent    = (const int*)d_in[0];
    const float* embed   = (const float*)d_in[1];
    const float* w_ih_f  = (const float*)d_in[2];
    const float* w_hh_f  = (const float*)d_in[3];
    const float* b_ih_f  = (const float*)d_in[4];
    const float* b_hh_f  = (const float*)d_in[5];
    const float* w_ih_r  = (const float*)d_in[6];
    const float* w_hh_r  = (const float*)d_in[7];
    const float* b_ih_r  = (const float*)d_in[8];
    const float* b_hh_r  = (const float*)d_in[9];
    const float* w_out   = (const float*)d_in[10];
    const float* b_out   = (const float*)d_in[11];
    const float* start_t = (const float*)d_in[12];
    const float* end_t   = (const float*)d_in[13];
    const float* trans   = (const float*)d_in[14];
    int* out = (int*)d_out;

    const size_t H_FLOATS  = (size_t)SLEN * BATCH * 256;   // 16777216
    const size_t F_FLOATS  = (size_t)SLEN * BATCH * NTAG;  //   262144
    const size_t ST_FLOATS = (size_t)2 * BATCH * 256;      //    32768
    const size_t FIXED = H_FLOATS + F_FLOATS + ST_FLOATS;

    // pick largest L (<=256) with DOUBLE-buffered Z fitting in ws
    int L = 0;
    for (int cand = 256; cand >= 32; cand >>= 1) {
        size_t need = ((size_t)2 * cand * BATCH * 1024 + FIXED) * sizeof(float);
        if (need <= ws_size) { L = cand; break; }
    }

    if (L > 0) {
        const int nch = SLEN / L;
        const int mtiles = (L * BATCH) / 128;
        float* Z0 = (float*)d_ws;
        float* Z1 = Z0 + (size_t)L * BATCH * 1024;
        float* H  = Z1 + (size_t)L * BATCH * 1024;
        float* F  = H + H_FLOATS;
        float* ST = F + F_FLOATS;
        float* Zb[2] = {Z0, Z1};

        gemm_zin<<<dim3(mtiles, 8), 256, 0, stream>>>(
            sent, embed, w_ih_f, w_ih_r, b_ih_f, b_hh_f, b_ih_r, b_hh_r,
            Zb[0], 0, SLEN - L);

        for (int c = 0; c < nch; ++c) {
            const int lbase_f = c * L;
            const int lbase_r = SLEN - (c + 1) * L;
            const int hasg = (c + 1 < nch);
            const int gbase_f = (c + 1) * L;
            const int gbase_r = SLEN - (c + 2) * L;
            const int grid = hasg ? (128 + mtiles * 8) : 128;
            fused_lstm_gemm<<<grid, 256, 0, stream>>>(
                sent, embed, w_ih_f, w_ih_r, b_ih_f, b_hh_f, b_ih_r, b_hh_r,
                Zb[(c + 1) & 1], hasg ? gbase_f : 0, hasg ? gbase_r : 0, mtiles,
                Zb[c & 1], w_hh_f, w_hh_r, H, ST, lbase_f, lbase_r, L,
                c == 0 ? 1 : 0);
        }

        emissions_k<<<1024, 256, 0, stream>>>(H, w_out, b_out, F);
        viterbi_k<<<64, 64, 0, stream>>>(F, start_t, end_t, trans, out);
    } else {
        // serial single-buffer fallback
        int Ls = SLEN;
        while (Ls > 32) {
            size_t need = ((size_t)Ls * BATCH * 1024 + FIXED) * sizeof(float);
            if (need <= ws_size) break;
            Ls >>= 1;
        }
        const int nch = SLEN / Ls;
        const int mtiles = (Ls * BATCH) / 128;
        float* Z  = (float*)d_ws;
        float* H  = Z + (size_t)Ls * BATCH * 1024;
        float* F  = H + H_FLOATS;
        float* ST = F + F_FLOATS;

        for (int c = 0; c < nch; ++c) {
            const int base_f = c * Ls;
            const int base_r = SLEN - (c + 1) * Ls;
            gemm_zin<<<dim3(mtiles, 8), 256, 0, stream>>>(
                sent, embed, w_ih_f, w_ih_r, b_ih_f, b_hh_f, b_ih_r, b_hh_r,
                Z, base_f, base_r);
            fused_lstm_gemm<<<128, 256, 0, stream>>>(
                sent, embed, w_ih_f, w_ih_r, b_ih_f, b_hh_f, b_ih_r, b_hh_r,
                Z, 0, 0, mtiles,
                Z, w_hh_f, w_hh_r, H, ST, base_f, base_r, Ls, c == 0 ? 1 : 0);
        }
        emissions_k<<<1024, 256, 0, stream>>>(H, w_out, b_out, F);
        viterbi_k<<<64, 64, 0, stream>>>(F, start_t, end_t, trans, out);
    }
}

// Round 13
// 1452.208 us; speedup vs baseline: 1.0587x; 1.0587x over previous
//
#include <hip/hip_runtime.h>
#include <cstdint>
#include <cstddef>

#define SLEN 1024
#define BATCH 64
#define EDIM 256
#define HDIM 128   // hidden per direction
#define GDIM 512   // 4*HDIM
#define NTAG 4

typedef float f2 __attribute__((ext_vector_type(2)));
typedef float f4 __attribute__((ext_vector_type(4)));

// ---------------------------------------------------------------------------
// ws layout (floats), double-buffered Z chunks:
//   Z0 : [L][B][1024]   Z1 : [L][B][1024]
//   H  : [S][B][256]    16777216
//   F  : [S][B][4]        262144
//   ST : [2][B][256]       32768
// ---------------------------------------------------------------------------

__device__ __forceinline__ float sigm_f(float x) {
    return 1.0f / (1.0f + __expf(-x));
}
__device__ __forceinline__ float tanh_f(float x) {
    return 1.0f - 2.0f / (1.0f + __expf(2.0f * x));
}

template <int CTRL>
__device__ __forceinline__ float quad_perm(float x) {
    return __int_as_float(
        __builtin_amdgcn_mov_dpp(__float_as_int(x), CTRL, 0xF, 0xF, true));
}
#define QP_XOR1 0xB1   // quad_perm [1,0,3,2]
#define QP_XOR2 0x4E   // quad_perm [2,3,0,1]

// ---------------------------------------------------------------------------
// gemm body (r12, conflict-free 4+4 micro-tile split). smem = 64KB (As|Bs).
// ---------------------------------------------------------------------------
__device__ __forceinline__ void gemm_body(
    float* smem, int mt, int nt,
    const int* __restrict__ sent, const float* __restrict__ embed,
    const float* __restrict__ w_ih_f, const float* __restrict__ w_ih_r,
    const float* __restrict__ b_ih_f, const float* __restrict__ b_hh_f,
    const float* __restrict__ b_ih_r, const float* __restrict__ b_hh_r,
    float* __restrict__ Z, int base_f, int base_r)
{
    float* As = smem;
    float* Bs = smem + 64 * 128;

    const int t   = threadIdx.x;
    const int dir = nt >> 2;
    const float* W  = dir ? w_ih_r : w_ih_f;
    const float* bi = dir ? b_ih_r : b_ih_f;
    const float* bh = dir ? b_hh_r : b_hh_f;
    const int ncol = (nt & 3) * 128;
    const int r0   = mt * 128;

    const int srow = t >> 1;
    const int half = t & 1;
    const int r_loc = r0 + srow;
    const int s_loc = r_loc >> 6;
    const int b_    = r_loc & 63;
    const int s_glob = (dir ? base_r : base_f) + s_loc;
    const int tok = sent[b_ * SLEN + s_glob];
    const float* arow = embed + (size_t)tok * EDIM + half * 32;
    const float* brow = W + (size_t)(ncol + srow) * EDIM + half * 32;

    const int tx = t & 15, ty = t >> 4;

    f2 acc[8][4];
    #pragma unroll
    for (int i = 0; i < 8; ++i)
        #pragma unroll
        for (int jj = 0; jj < 4; ++jj) { acc[i][jj] = (f2)(0.0f); }

    for (int kt = 0; kt < 4; ++kt) {
        const int k0 = kt * 64;
        __syncthreads();
        #pragma unroll
        for (int i = 0; i < 8; ++i) {
            float4 v = *(const float4*)(arow + k0 + i * 4);
            int kk = half * 32 + i * 4;
            As[(kk + 0) * 128 + srow] = v.x;
            As[(kk + 1) * 128 + srow] = v.y;
            As[(kk + 2) * 128 + srow] = v.z;
            As[(kk + 3) * 128 + srow] = v.w;
        }
        #pragma unroll
        for (int i = 0; i < 8; ++i) {
            float4 v = *(const float4*)(brow + k0 + i * 4);
            int kk = half * 32 + i * 4;
            Bs[(kk + 0) * 128 + srow] = v.x;
            Bs[(kk + 1) * 128 + srow] = v.y;
            Bs[(kk + 2) * 128 + srow] = v.z;
            Bs[(kk + 3) * 128 + srow] = v.w;
        }
        __syncthreads();

        #pragma unroll 8
        for (int k = 0; k < 64; ++k) {
            const f4 a0 = *(const f4*)&As[k * 128 + ty * 4];
            const f4 a1 = *(const f4*)&As[k * 128 + 64 + ty * 4];
            const f4 bq0 = *(const f4*)&Bs[k * 128 + tx * 4];
            const f4 bq1 = *(const f4*)&Bs[k * 128 + 64 + tx * 4];
            float av[8] = {a0.x, a0.y, a0.z, a0.w, a1.x, a1.y, a1.z, a1.w};
            f2 bv[4];
            bv[0] = __builtin_shufflevector(bq0, bq0, 0, 1);
            bv[1] = __builtin_shufflevector(bq0, bq0, 2, 3);
            bv[2] = __builtin_shufflevector(bq1, bq1, 0, 1);
            bv[3] = __builtin_shufflevector(bq1, bq1, 2, 3);
            #pragma unroll
            for (int i = 0; i < 8; ++i) {
                f2 as; as.x = av[i]; as.y = av[i];
                #pragma unroll
                for (int jj = 0; jj < 4; ++jj)
                    acc[i][jj] += as * bv[jj];   // v_pk_fma_f32
            }
        }
    }

    float bias0[4], bias1[4];
    #pragma unroll
    for (int j = 0; j < 4; ++j) {
        bias0[j] = bi[ncol + tx * 4 + j] + bh[ncol + tx * 4 + j];
        bias1[j] = bi[ncol + 64 + tx * 4 + j] + bh[ncol + 64 + tx * 4 + j];
    }

    #pragma unroll
    for (int i = 0; i < 8; ++i) {
        const int row = r0 + ((i < 4) ? (ty * 4 + i) : (64 + ty * 4 + i - 4));
        float* zp = Z + (size_t)row * 1024 + dir * 512 + ncol;
        float4 o0, o1;
        o0.x = acc[i][0].x + bias0[0]; o0.y = acc[i][0].y + bias0[1];
        o0.z = acc[i][1].x + bias0[2]; o0.w = acc[i][1].y + bias0[3];
        o1.x = acc[i][2].x + bias1[0]; o1.y = acc[i][2].y + bias1[1];
        o1.z = acc[i][3].x + bias1[2]; o1.w = acc[i][3].y + bias1[3];
        *(float4*)(zp + tx * 4)      = o0;
        *(float4*)(zp + 64 + tx * 4) = o1;
    }
}

// ---------------------------------------------------------------------------
// LSTM body (v9): r11 z-in-regs structure (measured best) + micro-cleanups:
// shufflevector subregister h-extraction (no repack movs), pointer-bump Z/H
// addressing (no per-step shl/add chains).
// ---------------------------------------------------------------------------
__device__ __forceinline__ void lstm_body(
    float* smem,
    const float* __restrict__ Z, const float* __restrict__ w_hh_f,
    const float* __restrict__ w_hh_r, float* __restrict__ H,
    float* __restrict__ ST, int base_f, int base_r, int L, int first)
{
    float* sh_h = smem;   // [2][160]

    const int bid = blockIdx.x;
    const int b   = bid & 63;
    const int dir = bid >> 6;
    const int q   = threadIdx.x;
    const int p   = q & 3;
    const int Q   = q >> 2;
    const int uA  = Q;
    const int uB  = Q + 64;

    const float* Whh = dir ? w_hh_r : w_hh_f;

    f2 w2[2][4][16];
    #pragma unroll
    for (int u2 = 0; u2 < 2; ++u2) {
        const int u = u2 ? uB : uA;
        #pragma unroll
        for (int g = 0; g < 4; ++g) {
            const f2* src =
                (const f2*)(Whh + ((size_t)(g * 128 + u) * 128 + p * 32));
            #pragma unroll
            for (int i = 0; i < 16; ++i) w2[u2][g][i] = src[i];
        }
    }

    float* stp = ST + (size_t)(dir * 64 + b) * 256;
    if (q < 128)
        sh_h[(q >> 5) * 36 + (q & 31)] = first ? 0.0f : stp[q];
    float cA = first ? 0.0f : stp[128 + uA];
    float cB = first ? 0.0f : stp[128 + uB];

    // pointer-bump Z addressing: step t's z at zp0 + t*zstride
    const ptrdiff_t zstride = dir ? -65536 : 65536;
    const float* zp0 = Z + (size_t)b * 1024 + dir * 512
                     + (dir ? (size_t)(L - 1) * 65536 : 0);
    // pointer-bump H addressing
    const ptrdiff_t hstride = dir ? -16384 : 16384;
    float* hg0 = H + ((size_t)(dir ? (base_r + L - 1) : base_f) * 64 + b) * 256
               + dir * 128;

    float zcur[4][2][4], znxt[4][2][4];
    {
        const float* zp = zp0;
        #pragma unroll
        for (int dt = 0; dt < 4; ++dt) {
            #pragma unroll
            for (int u2 = 0; u2 < 2; ++u2)
                #pragma unroll
                for (int g = 0; g < 4; ++g)
                    zcur[dt][u2][g] = zp[g * 128 + (u2 ? uB : uA)];
            zp += zstride;
        }
    }
    __syncthreads();

    float hAo[4], hBo[4];

    for (int t0 = 0; t0 < L; t0 += 4) {
        const bool more = (t0 + 4 < L);
        if (more) {
            const float* zp = zp0 + (ptrdiff_t)(t0 + 4) * zstride;
            #pragma unroll
            for (int dt = 0; dt < 4; ++dt) {
                #pragma unroll
                for (int u2 = 0; u2 < 2; ++u2)
                    #pragma unroll
                    for (int g = 0; g < 4; ++g)
                        znxt[dt][u2][g] = zp[g * 128 + (u2 ? uB : uA)];
                zp += zstride;
            }
        }

        #pragma unroll
        for (int dt = 0; dt < 4; ++dt) {
            const int t = t0 + dt;
            const f4* hp = (const f4*)(sh_h + (t & 1) * 160 + p * 36);
            f2 hv[16];
            #pragma unroll
            for (int i = 0; i < 8; ++i) {
                f4 v = hp[i];
                hv[2 * i]     = __builtin_shufflevector(v, v, 0, 1);
                hv[2 * i + 1] = __builtin_shufflevector(v, v, 2, 3);
            }
            float z8[2][4];
            #pragma unroll
            for (int u2 = 0; u2 < 2; ++u2) {
                #pragma unroll
                for (int g = 0; g < 4; ++g) {
                    f2 a = (f2)(0.0f);
                    #pragma unroll
                    for (int i = 0; i < 16; ++i)
                        a += w2[u2][g][i] * hv[i];   // v_pk_fma_f32
                    float v = a.x + a.y;
                    v += quad_perm<QP_XOR1>(v);
                    v += quad_perm<QP_XOR2>(v);
                    z8[u2][g] = v + zcur[dt][u2][g];
                }
            }
            float iA = sigm_f(z8[0][0]), fA = sigm_f(z8[0][1]);
            float gA = tanh_f(z8[0][2]), oA = sigm_f(z8[0][3]);
            cA = fA * cA + iA * gA;
            float hA = oA * tanh_f(cA);
            float iB = sigm_f(z8[1][0]), fB = sigm_f(z8[1][1]);
            float gB = tanh_f(z8[1][2]), oB = sigm_f(z8[1][3]);
            cB = fB * cB + iB * gB;
            float hB = oB * tanh_f(cB);
            hAo[dt] = hA; hBo[dt] = hB;

            if (p == 0) {
                float* hn = sh_h + ((t + 1) & 1) * 160;
                hn[(uA >> 5) * 36 + (uA & 31)] = hA;
                hn[(uB >> 5) * 36 + (uB & 31)] = hB;
            }
            __syncthreads();
        }

        if (p == 0) {
            float* hg = hg0 + (ptrdiff_t)t0 * hstride;
            #pragma unroll
            for (int dt = 0; dt < 4; ++dt) {
                hg[uA] = hAo[dt];
                hg[uB] = hBo[dt];
                hg += hstride;
            }
        }
        if (more) {
            #pragma unroll
            for (int dt = 0; dt < 4; ++dt)
                #pragma unroll
                for (int u2 = 0; u2 < 2; ++u2)
                    #pragma unroll
                    for (int g = 0; g < 4; ++g)
                        zcur[dt][u2][g] = znxt[dt][u2][g];
        }
    }

    if (p == 0) {
        stp[uA] = hAo[3];  stp[uB] = hBo[3];
        stp[128 + uA] = cA; stp[128 + uB] = cB;
    }
}

// ---------------------------------------------------------------------------
// Fused kernel: blocks 0..127 = lstm chunk c (Zr); blocks 128.. = gemm
// chunk c+1 (Zw). Shared 64KB smem union.
// ---------------------------------------------------------------------------
__global__ __launch_bounds__(256) void fused_lstm_gemm(
    const int* __restrict__ sent, const float* __restrict__ embed,
    const float* __restrict__ w_ih_f, const float* __restrict__ w_ih_r,
    const float* __restrict__ b_ih_f, const float* __restrict__ b_hh_f,
    const float* __restrict__ b_ih_r, const float* __restrict__ b_hh_r,
    float* __restrict__ Zw, int gbase_f, int gbase_r, int mtiles,
    const float* __restrict__ Zr, const float* __restrict__ w_hh_f,
    const float* __restrict__ w_hh_r, float* __restrict__ H,
    float* __restrict__ ST, int lbase_f, int lbase_r, int L, int first)
{
    __shared__ __align__(16) float smem[64 * 128 * 2];   // 64 KB

    if (blockIdx.x < 128) {
        lstm_body(smem, Zr, w_hh_f, w_hh_r, H, ST, lbase_f, lbase_r, L, first);
    } else {
        const int g  = blockIdx.x - 128;
        const int mt = g % mtiles;
        const int nt = g / mtiles;
        gemm_body(smem, mt, nt, sent, embed, w_ih_f, w_ih_r,
                  b_ih_f, b_hh_f, b_ih_r, b_hh_r, Zw, gbase_f, gbase_r);
    }
}

// standalone gemm (pipeline prologue)
__global__ __launch_bounds__(256) void gemm_zin(
    const int* __restrict__ sent, const float* __restrict__ embed,
    const float* __restrict__ w_ih_f, const float* __restrict__ w_ih_r,
    const float* __restrict__ b_ih_f, const float* __restrict__ b_hh_f,
    const float* __restrict__ b_ih_r, const float* __restrict__ b_hh_r,
    float* __restrict__ Z, int base_f, int base_r)
{
    __shared__ __align__(16) float smem[64 * 128 * 2];
    gemm_body(smem, blockIdx.x, blockIdx.y, sent, embed, w_ih_f, w_ih_r,
              b_ih_f, b_hh_f, b_ih_r, b_hh_r, Z, base_f, base_r);
}

// ---------------------------------------------------------------------------
// Kernel 3: emissions  F[r][t] = H[r] . w_out[t] + b_out[t]
// ---------------------------------------------------------------------------
__global__ __launch_bounds__(256) void emissions_k(
    const float* __restrict__ H, const float* __restrict__ w_out,
    const float* __restrict__ b_out, float* __restrict__ F)
{
    const int gid = blockIdx.x * 256 + threadIdx.x;
    const int r   = gid >> 2;
    const int tg  = gid & 3;
    const float4* h4 = (const float4*)(H + (size_t)r * 256);
    const float4* w4 = (const float4*)(w_out + (size_t)tg * 256);
    float a0 = 0.f, a1 = 0.f, a2 = 0.f, a3 = 0.f;
    #pragma unroll 8
    for (int k = 0; k < 64; ++k) {
        float4 h = h4[k], w = w4[k];
        a0 = fmaf(h.x, w.x, a0); a1 = fmaf(h.y, w.y, a1);
        a2 = fmaf(h.z, w.z, a2); a3 = fmaf(h.w, w.w, a3);
    }
    F[gid] = ((a0 + a1) + (a2 + a3)) + b_out[tg];
}

// ---------------------------------------------------------------------------
// Kernel 4: Viterbi. One block (1 wave) per batch.
// ---------------------------------------------------------------------------
__device__ __forceinline__ unsigned compose_map(unsigned a, unsigned b) {
    unsigned r = 0;
    #pragma unroll
    for (int jj = 0; jj < 4; ++jj) {
        unsigned bj = (b >> (jj * 8)) & 3u;
        unsigned aj = (a >> (bj * 8)) & 3u;
        r |= aj << (jj * 8);
    }
    return r;
}

__global__ __launch_bounds__(64) void viterbi_k(
    const float* __restrict__ F, const float* __restrict__ start_t,
    const float* __restrict__ end_t, const float* __restrict__ trans,
    int* __restrict__ out)
{
    const int b    = blockIdx.x;
    const int lane = threadIdx.x;
    __shared__ __align__(16) float sfeat[SLEN][NTAG];
    __shared__ unsigned sbp[SLEN];

    #pragma unroll
    for (int i = 0; i < 16; ++i) {
        int s = i * 64 + lane;
        ((float4*)sfeat)[s] = *(const float4*)(F + ((size_t)s * BATCH + b) * NTAG);
    }
    __syncthreads();

    const int cur = lane & 3;
    float tr0 = trans[0 * 4 + cur], tr1 = trans[1 * 4 + cur];
    float tr2 = trans[2 * 4 + cur], tr3 = trans[3 * 4 + cur];
    float sc = start_t[cur] + sfeat[0][cur];

    for (int s = 1; s < SLEN; ++s) {
        float ft = sfeat[s][cur];
        float s0 = __shfl(sc, 0), s1 = __shfl(sc, 1);
        float s2 = __shfl(sc, 2), s3 = __shfl(sc, 3);
        float c0 = s0 + tr0, c1 = s1 + tr1, c2 = s2 + tr2, c3 = s3 + tr3;
        float best = c0; int arg = 0;
        if (c1 > best) { best = c1; arg = 1; }
        if (c2 > best) { best = c2; arg = 2; }
        if (c3 > best) { best = c3; arg = 3; }
        sc = best + ft;
        unsigned bp = (unsigned)arg;
        unsigned b0 = __shfl(bp, 0), b1 = __shfl(bp, 1);
        unsigned b2 = __shfl(bp, 2), b3 = __shfl(bp, 3);
        if (lane == 0) sbp[s] = b0 | (b1 << 8) | (b2 << 16) | (b3 << 24);
    }
    sc += end_t[cur];
    float f0 = __shfl(sc, 0), f1 = __shfl(sc, 1);
    float f2v = __shfl(sc, 2), f3 = __shfl(sc, 3);
    int last = 0; float bb = f0;
    if (f1 > bb)  { bb = f1;  last = 1; }
    if (f2v > bb) { bb = f2v; last = 2; }
    if (f3 > bb)  { bb = f3;  last = 3; }
    __syncthreads();

    unsigned m[16];
    #pragma unroll
    for (int k = 0; k < 16; ++k) {
        int s = lane * 16 + k;
        m[k] = (s >= 1) ? sbp[s] : 0x03020100u;
    }
    unsigned G = m[15];
    #pragma unroll
    for (int k = 14; k >= 0; --k) G = compose_map(m[k], G);
    unsigned R = G;
    #pragma unroll
    for (int d = 1; d < 64; d <<= 1) {
        unsigned oo = __shfl_down(R, d);
        if (lane + d < 64) R = compose_map(R, oo);
    }
    unsigned P = __shfl_down(R, 1);
    if (lane == 63) P = 0x03020100u;

    int tcur = (int)((P >> (last * 8)) & 3u);
    int* ob = out + b * SLEN + lane * 16;
    ob[15] = tcur;
    #pragma unroll
    for (int k = 15; k >= 1; --k) {
        tcur = (int)((m[k] >> (tcur * 8)) & 3u);
        ob[k - 1] = tcur;
    }
}

// ---------------------------------------------------------------------------
extern "C" void kernel_launch(void* const* d_in, const int* in_sizes, int n_in,
                              void* d_out, int out_size, void* d_ws, size_t ws_size,
                              hipStream_t stream)
{
    const int*   sent    = (const int*)d_in[0];
    const float* embed   = (const float*)d_in[1];
    const float* w_ih_f  = (const float*)d_in[2];
    const float* w_hh_f  = (const float*)d_in[3];
    const float* b_ih_f  = (const float*)d_in[4];
    const float* b_hh_f  = (const float*)d_in[5];
    const float* w_ih_r  = (const float*)d_in[6];
    const float* w_hh_r  = (const float*)d_in[7];
    const float* b_ih_r  = (const float*)d_in[8];
    const float* b_hh_r  = (const float*)d_in[9];
    const float* w_out   = (const float*)d_in[10];
    const float* b_out   = (const float*)d_in[11];
    const float* start_t = (const float*)d_in[12];
    const float* end_t   = (const float*)d_in[13];
    const float* trans   = (const float*)d_in[14];
    int* out = (int*)d_out;

    const size_t H_FLOATS  = (size_t)SLEN * BATCH * 256;   // 16777216
    const size_t F_FLOATS  = (size_t)SLEN * BATCH * NTAG;  //   262144
    const size_t ST_FLOATS = (size_t)2 * BATCH * 256;      //    32768
    const size_t FIXED = H_FLOATS + F_FLOATS + ST_FLOATS;

    // pick largest L (<=256) with DOUBLE-buffered Z fitting in ws
    int L = 0;
    for (int cand = 256; cand >= 32; cand >>= 1) {
        size_t need = ((size_t)2 * cand * BATCH * 1024 + FIXED) * sizeof(float);
        if (need <= ws_size) { L = cand; break; }
    }

    if (L > 0) {
        const int nch = SLEN / L;
        const int mtiles = (L * BATCH) / 128;
        float* Z0 = (float*)d_ws;
        float* Z1 = Z0 + (size_t)L * BATCH * 1024;
        float* H  = Z1 + (size_t)L * BATCH * 1024;
        float* F  = H + H_FLOATS;
        float* ST = F + F_FLOATS;
        float* Zb[2] = {Z0, Z1};

        gemm_zin<<<dim3(mtiles, 8), 256, 0, stream>>>(
            sent, embed, w_ih_f, w_ih_r, b_ih_f, b_hh_f, b_ih_r, b_hh_r,
            Zb[0], 0, SLEN - L);

        for (int c = 0; c < nch; ++c) {
            const int lbase_f = c * L;
            const int lbase_r = SLEN - (c + 1) * L;
            const int hasg = (c + 1 < nch);
            const int gbase_f = (c + 1) * L;
            const int gbase_r = SLEN - (c + 2) * L;
            const int grid = hasg ? (128 + mtiles * 8) : 128;
            fused_lstm_gemm<<<grid, 256, 0, stream>>>(
                sent, embed, w_ih_f, w_ih_r, b_ih_f, b_hh_f, b_ih_r, b_hh_r,
                Zb[(c + 1) & 1], hasg ? gbase_f : 0, hasg ? gbase_r : 0, mtiles,
                Zb[c & 1], w_hh_f, w_hh_r, H, ST, lbase_f, lbase_r, L,
                c == 0 ? 1 : 0);
        }

        emissions_k<<<1024, 256, 0, stream>>>(H, w_out, b_out, F);
        viterbi_k<<<64, 64, 0, stream>>>(F, start_t, end_t, trans, out);
    } else {
        // serial single-buffer fallback
        int Ls = SLEN;
        while (Ls > 32) {
            size_t need = ((size_t)Ls * BATCH * 1024 + FIXED) * sizeof(float);
            if (need <= ws_size) break;
            Ls >>= 1;
        }
        const int nch = SLEN / Ls;
        const int mtiles = (Ls * BATCH) / 128;
        float* Z  = (float*)d_ws;
        float* H  = Z + (size_t)Ls * BATCH * 1024;
        float* F  = H + H_FLOATS;
        float* ST = F + F_FLOATS;

        for (int c = 0; c < nch; ++c) {
            const int base_f = c * Ls;
            const int base_r = SLEN - (c + 1) * Ls;
            gemm_zin<<<dim3(mtiles, 8), 256, 0, stream>>>(
                sent, embed, w_ih_f, w_ih_r, b_ih_f, b_hh_f, b_ih_r, b_hh_r,
                Z, base_f, base_r);
            fused_lstm_gemm<<<128, 256, 0, stream>>>(
                sent, embed, w_ih_f, w_ih_r, b_ih_f, b_hh_f, b_ih_r, b_hh_r,
                Z, 0, 0, mtiles,
                Z, w_hh_f, w_hh_r, H, ST, base_f, base_r, Ls, c == 0 ? 1 : 0);
        }
        emissions_k<<<1024, 256, 0, stream>>>(H, w_out, b_out, F);
        viterbi_k<<<64, 64, 0, stream>>>(F, start_t, end_t, trans, out);
    }
}